// Round 13
// baseline (115.077 us; speedup 1.0000x reference)
//
#include <hip/hip_runtime.h>
#include <hip/hip_bf16.h>

typedef __bf16 bf16x8 __attribute__((ext_vector_type(8)));
typedef float  f32x4  __attribute__((ext_vector_type(4)));
typedef float  f32x16 __attribute__((ext_vector_type(16)));

#define NB 16
#define NC 32
#define NH 32
#define NW 2048
#define NK (NC*NH)   // 1024
#define LOG2E 1.4426950408889634f

static __device__ __forceinline__ unsigned int pk2(float a, float b) {
    union { __bf16 h[2]; unsigned int u; } z;
    z.h[0] = (__bf16)a; z.h[1] = (__bf16)b;
    return z.u;
}

// ---------------------------------------------------------------------------
// Kernel 1: QKV projection — EXACT R2 structure (benched ~32 us steady).
// 4-way K-split, scalar fp32 A loads, fp32 weight float4 loads (cvt to bf16
// in-register), single-round 48 KB LDS combine. Only change vs R2: wq/bq are
// scaled by log2e so the fixed-max attention can use native exp2.
// NOTE: wptr[] pre-encodes the 16-row offset for odd ntiles -> B-frag row
// index is JUST lr (R12's ((nt&1)*16+lr) double-offset was the bug).
// ---------------------------------------------------------------------------
__global__ __launch_bounds__(256) void proj_kernel(
    const float* __restrict__ x,
    const float* __restrict__ wq, const float* __restrict__ bq,
    const float* __restrict__ wk, const float* __restrict__ bk,
    const float* __restrict__ wv, const float* __restrict__ bv,
    __bf16* __restrict__ qT, __bf16* __restrict__ kT, __bf16* __restrict__ vT)
{
    const int b    = blockIdx.x >> 6;
    const int wt   = blockIdx.x & 63;
    const int wave = threadIdx.x >> 6;       // = K slice
    const int lane = threadIdx.x & 63;
    const int g    = lane >> 4;
    const int lr   = lane & 15;
    const int w0   = wt * 32;

    const float* xb = x + (size_t)b * NK * NW;
    const float* wptr[6] = { wq, wq + 16*NK, wk, wk + 16*NK, wv, wv + 16*NK };
    const int k0 = wave * 256;

    f32x4 acc[2][6];
    #pragma unroll
    for (int mt = 0; mt < 2; ++mt)
        #pragma unroll
        for (int nt = 0; nt < 6; ++nt)
            acc[mt][nt] = f32x4{0.f, 0.f, 0.f, 0.f};

    for (int ki = 0; ki < 8; ++ki) {
        const int kk = k0 + ki * 32;
        bf16x8 af[2];
        #pragma unroll
        for (int mt = 0; mt < 2; ++mt) {
            const float* p = xb + (size_t)(kk + g*8) * NW + (w0 + mt*16 + lr);
            bf16x8 t;
            #pragma unroll
            for (int j = 0; j < 8; ++j) t[j] = (__bf16)p[(size_t)j * NW];
            af[mt] = t;
        }
        bf16x8 bfv[6];
        #pragma unroll
        for (int nt = 0; nt < 6; ++nt) {
            const float sc = (nt < 2) ? LOG2E : 1.0f;   // fold log2e into wq
            const float* p = wptr[nt] + (size_t)lr * NK + kk + g*8;
            float4 lo = *(const float4*)p;
            float4 hi = *(const float4*)(p + 4);
            bf16x8 t;
            t[0]=(__bf16)(lo.x*sc); t[1]=(__bf16)(lo.y*sc);
            t[2]=(__bf16)(lo.z*sc); t[3]=(__bf16)(lo.w*sc);
            t[4]=(__bf16)(hi.x*sc); t[5]=(__bf16)(hi.y*sc);
            t[6]=(__bf16)(hi.z*sc); t[7]=(__bf16)(hi.w*sc);
            bfv[nt] = t;
        }
        #pragma unroll
        for (int mt = 0; mt < 2; ++mt)
            #pragma unroll
            for (int nt = 0; nt < 6; ++nt)
                acc[mt][nt] = __builtin_amdgcn_mfma_f32_16x16x32_bf16(
                    af[mt], bfv[nt], acc[mt][nt], 0, 0, 0);
    }

    // ---- combine the 4 K-slices through LDS (single round, 48 KB) ----
    __shared__ f32x4 part[4][12][64];
    #pragma unroll
    for (int mt = 0; mt < 2; ++mt)
        #pragma unroll
        for (int nt = 0; nt < 6; ++nt)
            part[wave][mt*6 + nt][lane] = acc[mt][nt];
    __syncthreads();

    const int mt     = wave & 1;
    const int ntbase = (wave >> 1) * 3;
    const float* biases[3] = { bq, bk, bv };
    #pragma unroll
    for (int nti = 0; nti < 3; ++nti) {
        const int nt = ntbase + nti;
        const int fi = mt*6 + nt;
        f32x4 s = part[0][fi][lane];
        #pragma unroll
        for (int sl = 1; sl < 4; ++sl) s += part[sl][fi][lane];
        const int pid = nt >> 1;                 // 0=q,1=k,2=v
        const int o   = (nt & 1) * 16 + lr;
        float bb = biases[pid][o];
        if (pid == 0) bb *= LOG2E;
        __bf16* dst = (pid == 0 ? qT : pid == 1 ? kT : vT) + (size_t)b * NW * NC;
        #pragma unroll
        for (int r = 0; r < 4; ++r) {
            const int w = w0 + mt*16 + g*4 + r;
            dst[(size_t)w * NC + o] = (__bf16)(s[r] + bb);
        }
    }
}

// ---------------------------------------------------------------------------
// Kernel 1b: vT [B][W][32] -> V [B][32][W]  (R2-verified, ~3 us)
// ---------------------------------------------------------------------------
__global__ __launch_bounds__(256) void vtrans_kernel(
    const __bf16* __restrict__ vT, __bf16* __restrict__ V)
{
    __shared__ __bf16 t[NC][136];
    const int b  = blockIdx.x >> 4;
    const int wc = blockIdx.x & 15;
    const int w0 = wc * 128;
    #pragma unroll
    for (int e = 0; e < 16; ++e) {
        int flat = e*256 + threadIdx.x;
        int wl = flat >> 5, c = flat & 31;
        t[c][wl] = vT[((size_t)b*NW + w0 + wl) * NC + c];
    }
    __syncthreads();
    #pragma unroll
    for (int e = 0; e < 16; ++e) {
        int flat = e*256 + threadIdx.x;
        int c = flat >> 7, wl = flat & 127;
        V[((size_t)b*NC + c) * NW + w0 + wl] = t[c][wl];
    }
}

// ---------------------------------------------------------------------------
// Kernel 2: flash attention (R10, unchanged): fixed-max softmax, sigma-
// permuted K rows (lane-local PV fragments), software-pipelined loop,
// exp2 via __builtin_amdgcn_exp2f, NT out stores.
// ---------------------------------------------------------------------------
__global__ __launch_bounds__(256) void attn_kernel(
    const float* __restrict__ x,
    const __bf16* __restrict__ qT, const __bf16* __restrict__ kT,
    const __bf16* __restrict__ V,
    float* __restrict__ out)
{
    const int b    = blockIdx.x >> 6;
    const int wt   = blockIdx.x & 63;
    const int w0   = wt * 32;
    const int wave = threadIdx.x >> 6;        // KV slice 0..3
    const int lane = threadIdx.x & 63;
    const int wl = lane & 31, hi = lane >> 5;
    const int swl = (wl & 0x13) | ((wl & 4) << 1) | ((wl & 8) >> 1);

    const __bf16* qTb = qT + (size_t)b * NW * NC;
    const __bf16* kTb = kT + (size_t)b * NW * NC;
    const __bf16* Vb  = V  + (size_t)b * NC * NW;

    const __bf16* qrow = qTb + (size_t)(w0 + wl) * NC;
    const bf16x8 qf0 = *(const bf16x8*)(qrow + hi*8);
    const bf16x8 qf1 = *(const bf16x8*)(qrow + 16 + hi*8);

    f32x16 acc, z16;
    #pragma unroll
    for (int r = 0; r < 16; ++r) { acc[r] = 0.f; z16[r] = 0.f; }
    float lsum = 0.f;

    const int vbeg = wave * 512;
    const __bf16* kbase = kTb + (size_t)swl * NC;
    const __bf16* vbase = Vb + (size_t)wl * NW;

#define KLD0(V0) (*(const bf16x8*)(kbase + (size_t)(V0) * NC + hi*8))
#define KLD1(V0) (*(const bf16x8*)(kbase + (size_t)(V0) * NC + 16 + hi*8))
#define VLD0(V0) (*(const bf16x8*)(vbase + (V0) + hi*8))
#define VLD1(V0) (*(const bf16x8*)(vbase + (V0) + 16 + hi*8))

    bf16x8 k0r = KLD0(vbeg), k1r = KLD1(vbeg);
    f32x16 s_cur = __builtin_amdgcn_mfma_f32_32x32x16_bf16(k0r, qf0, z16, 0, 0, 0);
    s_cur = __builtin_amdgcn_mfma_f32_32x32x16_bf16(k1r, qf1, s_cur, 0, 0, 0);
    k0r = KLD0(vbeg + 32); k1r = KLD1(vbeg + 32);
    bf16x8 v0r = VLD0(vbeg), v1r = VLD1(vbeg);

    #pragma unroll
    for (int it = 0; it < 16; ++it) {
        f32x16 s_next;
        if (it < 15) {
            s_next = __builtin_amdgcn_mfma_f32_32x32x16_bf16(k0r, qf0, z16, 0, 0, 0);
            s_next = __builtin_amdgcn_mfma_f32_32x32x16_bf16(k1r, qf1, s_next, 0, 0, 0);
        }
        if (it < 14) {
            const int vn = vbeg + (it + 2) * 32;
            k0r = KLD0(vn); k1r = KLD1(vn);
        }

        float p[16];
        #pragma unroll
        for (int r = 0; r < 16; ++r) p[r] = __builtin_amdgcn_exp2f(s_cur[r]);
        float ts[8];
        #pragma unroll
        for (int r = 0; r < 8; ++r) ts[r] = p[r] + p[r+8];
        #pragma unroll
        for (int r = 0; r < 4; ++r) ts[r] += ts[r+4];
        lsum += (ts[0] + ts[1]) + (ts[2] + ts[3]);

        union { unsigned int u[4]; bf16x8 v; } pfa, pfb;
        #pragma unroll
        for (int i = 0; i < 4; ++i) pfa.u[i] = pk2(p[2*i],     p[2*i + 1]);
        #pragma unroll
        for (int i = 0; i < 4; ++i) pfb.u[i] = pk2(p[8 + 2*i], p[8 + 2*i + 1]);

        acc = __builtin_amdgcn_mfma_f32_32x32x16_bf16(v0r, pfa.v, acc, 0, 0, 0);
        acc = __builtin_amdgcn_mfma_f32_32x32x16_bf16(v1r, pfb.v, acc, 0, 0, 0);

        if (it < 15) {
            const int vn = vbeg + (it + 1) * 32;
            v0r = VLD0(vn); v1r = VLD1(vn);
            s_cur = s_next;
        }
    }
#undef KLD0
#undef KLD1
#undef VLD0
#undef VLD1
    lsum += __shfl_xor(lsum, 32);

    __shared__ float sl[4][32];
    __shared__ float sO[4][32][33];
    __shared__ float Of[32][33];

    if (hi == 0) sl[wave][wl] = lsum;
    #pragma unroll
    for (int r = 0; r < 16; ++r) {
        const int c = (r & 3) + 8*(r >> 2) + 4*hi;
        sO[wave][c][wl] = acc[r];
    }
    __syncthreads();

    {
        const int w  = threadIdx.x & 31;
        const int cg = threadIdx.x >> 5;
        const float L = (sl[0][w] + sl[1][w]) + (sl[2][w] + sl[3][w]);
        const float rL = 1.0f / L;
        #pragma unroll
        for (int cc = 0; cc < 4; ++cc) {
            const int c = cg * 4 + cc;
            const float o = ((sO[0][c][w] + sO[1][c][w]) +
                             (sO[2][c][w] + sO[3][c][w]));
            Of[c][w] = o * rL;
        }
    }
    __syncthreads();

    const float* xb = x   + (size_t)b * NC * NH * NW + w0;
    float*       ob = out + (size_t)b * NC * NH * NW + w0;
    const int chunk = threadIdx.x & 7;
    #pragma unroll
    for (int it = 0; it < 32; ++it) {
        const int row = it*32 + (threadIdx.x >> 3);
        const int c = row >> 5, h = row & 31;
        const size_t off = ((size_t)c * NH + h) * NW + chunk*4;
        const f32x4 xv = *(const f32x4*)(xb + off);
        f32x4 ov;
        ov[0] = Of[c][chunk*4 + 0] + xv[0];
        ov[1] = Of[c][chunk*4 + 1] + xv[1];
        ov[2] = Of[c][chunk*4 + 2] + xv[2];
        ov[3] = Of[c][chunk*4 + 3] + xv[3];
        __builtin_nontemporal_store(ov, (f32x4*)(ob + off));
    }
}

extern "C" void kernel_launch(void* const* d_in, const int* in_sizes, int n_in,
                              void* d_out, int out_size, void* d_ws, size_t ws_size,
                              hipStream_t stream)
{
    const float* x  = (const float*)d_in[0];
    const float* wq = (const float*)d_in[1];
    const float* bq = (const float*)d_in[2];
    const float* wk = (const float*)d_in[3];
    const float* bk = (const float*)d_in[4];
    const float* wv = (const float*)d_in[5];
    const float* bv = (const float*)d_in[6];
    float* out = (float*)d_out;

    // ws layout (bf16): qT [B][W][32] @0, kT @2MB, vT @4MB, V [B][32][W] @6MB
    char* ws = (char*)d_ws;
    __bf16* qT = (__bf16*)(ws);
    __bf16* kT = (__bf16*)(ws + (2u << 20));
    __bf16* vT = (__bf16*)(ws + (4u << 20));
    __bf16* V  = (__bf16*)(ws + (6u << 20));

    hipLaunchKernelGGL(proj_kernel, dim3(NB * 64), dim3(256), 0, stream,
                       x, wq, bq, wk, bk, wv, bv, qT, kT, vT);
    hipLaunchKernelGGL(vtrans_kernel, dim3(NB * 16), dim3(256), 0, stream, vT, V);
    hipLaunchKernelGGL(attn_kernel, dim3(NB * 64), dim3(256), 0, stream,
                       x, qT, kT, V, out);
}

// Round 14
// 93.919 us; speedup vs baseline: 1.2253x; 1.2253x over previous
//
#include <hip/hip_runtime.h>
#include <hip/hip_bf16.h>

typedef __bf16 bf16x8 __attribute__((ext_vector_type(8)));
typedef float  f32x4  __attribute__((ext_vector_type(4)));
typedef float  f32x16 __attribute__((ext_vector_type(16)));

#define NB 16
#define NC 32
#define NH 32
#define NW 2048
#define NK (NC*NH)   // 1024
#define LOG2E 1.4426950408889634f
#define KP 40        // LDS k-pitch (bf16) for the [w][k] tile

static __device__ __forceinline__ unsigned int pk2(float a, float b) {
    union { __bf16 h[2]; unsigned int u; } z;
    z.h[0] = (__bf16)a; z.h[1] = (__bf16)b;
    return z.u;
}

// ---------------------------------------------------------------------------
// Kernel 0: weights -> bf16. wb layout [3][32][1024]; wq scaled by log2e.
// ---------------------------------------------------------------------------
__global__ __launch_bounds__(256) void wprep_kernel(
    const float* __restrict__ wq, const float* __restrict__ wk,
    const float* __restrict__ wv, __bf16* __restrict__ wb)
{
    const int i = blockIdx.x * 256 + threadIdx.x;        // 24576 float4 units
    const float* srcs[3] = { wq, wk, wv };
    float4 v = *(const float4*)(srcs[i >> 13] + (size_t)(i & 8191) * 4);
    const float sc = (i >> 13) == 0 ? LOG2E : 1.0f;
    union { __bf16 h[4]; unsigned long long u; } z;
    z.h[0] = (__bf16)(v.x * sc); z.h[1] = (__bf16)(v.y * sc);
    z.h[2] = (__bf16)(v.z * sc); z.h[3] = (__bf16)(v.w * sc);
    *(unsigned long long*)(wb + (size_t)i * 4) = z.u;
}

// ---------------------------------------------------------------------------
// Kernel 1 (v4): QKV projection, NO K-split.
// Block = 384 thr (6 waves) covers 32 w; wave nt owns ONE 16-channel output
// tile (q0,q1,k0,k1,v0,v1) and accumulates over ALL 1024 k. Per 32k step the
// block stages a shared 32w x 32k x-slab: 256 threads do row-linear float4
// loads (coalesced 128B), cvt->bf16, transposed ds_write_b16 into [w][40k].
// A-frag = single ds_read_b128. B-frags from bf16 wb (L2), reg-double-buffed.
// LDS = 5 KB (2 x 2.5 KB dbuf) -> 5 blocks/CU = 30 waves/CU (~94% occup).
// Next-step global loads issued before this step's MFMAs (latency hidden).
// ---------------------------------------------------------------------------
__global__ __launch_bounds__(384) void proj_kernel(
    const float* __restrict__ x, const __bf16* __restrict__ wb,
    const float* __restrict__ bq, const float* __restrict__ bk,
    const float* __restrict__ bv,
    __bf16* __restrict__ qT, __bf16* __restrict__ kT, __bf16* __restrict__ V)
{
    const int b    = blockIdx.x >> 6;
    const int wt   = blockIdx.x & 63;
    const int nt   = threadIdx.x >> 6;       // wave = output ntile 0..5
    const int lane = threadIdx.x & 63;
    const int g    = lane >> 4;
    const int lr   = lane & 15;
    const int w0   = wt * 32;

    __shared__ __bf16 tile[2][32][KP];       // [buf][w][k], 5 KB total

    const float* xb = x + (size_t)b * NK * NW;

    // staging map (threads 0..255): k-row = t>>3, w-chunk = (t&7)*4
    const int skr = threadIdx.x >> 3;
    const int swc = (threadIdx.x & 7) * 4;
    const bool stager = (threadIdx.x < 256);
    const float* xs = xb + w0 + swc;

    // B-frag source: wb section (nt>>1), row (nt&1)*16 + lr
    const __bf16* wrow = wb + (size_t)(nt >> 1) * 32768
                            + (size_t)((nt & 1) * 16 + lr) * NK;

    f32x4 acc0 = {0.f,0.f,0.f,0.f}, acc1 = {0.f,0.f,0.f,0.f};

    // ---- prologue: stage step 0, load B(0) ----
    f32x4 xv;
    if (stager) {
        xv = *(const f32x4*)(xs + (size_t)skr * NW);
        __bf16* wp = &tile[0][swc][skr];
        wp[0*KP] = (__bf16)xv[0]; wp[1*KP] = (__bf16)xv[1];
        wp[2*KP] = (__bf16)xv[2]; wp[3*KP] = (__bf16)xv[3];
    }
    bf16x8 Bcur = *(const bf16x8*)(wrow + g*8);
    __syncthreads();

    for (int s = 0; s < 32; ++s) {
        const int cur = s & 1;
        // issue next step's global loads first (hidden under consume)
        f32x4 xn;
        if (s < 31 && stager)
            xn = *(const f32x4*)(xs + (size_t)((s+1)*32 + skr) * NW);
        bf16x8 Bnext;
        if (s < 31)
            Bnext = *(const bf16x8*)(wrow + (s+1)*32 + g*8);

        // consume: A-frags via ds_read_b128, 2 MFMAs
        const bf16x8 af0 = *(const bf16x8*)&tile[cur][lr][g*8];
        const bf16x8 af1 = *(const bf16x8*)&tile[cur][16 + lr][g*8];
        acc0 = __builtin_amdgcn_mfma_f32_16x16x32_bf16(af0, Bcur, acc0, 0, 0, 0);
        acc1 = __builtin_amdgcn_mfma_f32_16x16x32_bf16(af1, Bcur, acc1, 0, 0, 0);

        // stage next step into the other buffer
        if (s < 31 && stager) {
            __bf16* wp = &tile[cur ^ 1][swc][skr];
            wp[0*KP] = (__bf16)xn[0]; wp[1*KP] = (__bf16)xn[1];
            wp[2*KP] = (__bf16)xn[2]; wp[3*KP] = (__bf16)xn[3];
        }
        Bcur = Bnext;
        __syncthreads();
    }

    // ---- epilogue: bias + store this wave's 16 channels x 32 w ----
    const int pid = nt >> 1;                 // 0=q,1=k,2=v
    const int o   = (nt & 1) * 16 + lr;
    const float* biases[3] = { bq, bk, bv };
    float bb = biases[pid][o];
    if (pid == 0) bb *= LOG2E;

    if (pid < 2) {
        __bf16* dst = (pid ? kT : qT) + (size_t)b * NW * NC;
        #pragma unroll
        for (int r = 0; r < 4; ++r) {
            dst[(size_t)(w0 +      g*4 + r) * NC + o] = (__bf16)(acc0[r] + bb);
            dst[(size_t)(w0 + 16 + g*4 + r) * NC + o] = (__bf16)(acc1[r] + bb);
        }
    } else {
        __bf16* dst = V + ((size_t)b * NC + o) * NW + w0;
        union { __bf16 h[4]; unsigned long long u; } z0, z1;
        #pragma unroll
        for (int r = 0; r < 4; ++r) {
            z0.h[r] = (__bf16)(acc0[r] + bb);
            z1.h[r] = (__bf16)(acc1[r] + bb);
        }
        *(unsigned long long*)(dst +      g*4) = z0.u;
        *(unsigned long long*)(dst + 16 + g*4) = z1.u;
    }
}

// ---------------------------------------------------------------------------
// Kernel 2: flash attention (R10, unchanged/verified): fixed-max softmax,
// sigma-permuted K rows (lane-local PV fragments), software-pipelined loop,
// exp2 via __builtin_amdgcn_exp2f, NT out stores.
// ---------------------------------------------------------------------------
__global__ __launch_bounds__(256) void attn_kernel(
    const float* __restrict__ x,
    const __bf16* __restrict__ qT, const __bf16* __restrict__ kT,
    const __bf16* __restrict__ V,
    float* __restrict__ out)
{
    const int b    = blockIdx.x >> 6;
    const int wt   = blockIdx.x & 63;
    const int w0   = wt * 32;
    const int wave = threadIdx.x >> 6;        // KV slice 0..3
    const int lane = threadIdx.x & 63;
    const int wl = lane & 31, hi = lane >> 5;
    const int swl = (wl & 0x13) | ((wl & 4) << 1) | ((wl & 8) >> 1);

    const __bf16* qTb = qT + (size_t)b * NW * NC;
    const __bf16* kTb = kT + (size_t)b * NW * NC;
    const __bf16* Vb  = V  + (size_t)b * NC * NW;

    const __bf16* qrow = qTb + (size_t)(w0 + wl) * NC;
    const bf16x8 qf0 = *(const bf16x8*)(qrow + hi*8);
    const bf16x8 qf1 = *(const bf16x8*)(qrow + 16 + hi*8);

    f32x16 acc, z16;
    #pragma unroll
    for (int r = 0; r < 16; ++r) { acc[r] = 0.f; z16[r] = 0.f; }
    float lsum = 0.f;

    const int vbeg = wave * 512;
    const __bf16* kbase = kTb + (size_t)swl * NC;
    const __bf16* vbase = Vb + (size_t)wl * NW;

#define KLD0(V0) (*(const bf16x8*)(kbase + (size_t)(V0) * NC + hi*8))
#define KLD1(V0) (*(const bf16x8*)(kbase + (size_t)(V0) * NC + 16 + hi*8))
#define VLD0(V0) (*(const bf16x8*)(vbase + (V0) + hi*8))
#define VLD1(V0) (*(const bf16x8*)(vbase + (V0) + 16 + hi*8))

    bf16x8 k0r = KLD0(vbeg), k1r = KLD1(vbeg);
    f32x16 s_cur = __builtin_amdgcn_mfma_f32_32x32x16_bf16(k0r, qf0, z16, 0, 0, 0);
    s_cur = __builtin_amdgcn_mfma_f32_32x32x16_bf16(k1r, qf1, s_cur, 0, 0, 0);
    k0r = KLD0(vbeg + 32); k1r = KLD1(vbeg + 32);
    bf16x8 v0r = VLD0(vbeg), v1r = VLD1(vbeg);

    #pragma unroll
    for (int it = 0; it < 16; ++it) {
        f32x16 s_next;
        if (it < 15) {
            s_next = __builtin_amdgcn_mfma_f32_32x32x16_bf16(k0r, qf0, z16, 0, 0, 0);
            s_next = __builtin_amdgcn_mfma_f32_32x32x16_bf16(k1r, qf1, s_next, 0, 0, 0);
        }
        if (it < 14) {
            const int vn = vbeg + (it + 2) * 32;
            k0r = KLD0(vn); k1r = KLD1(vn);
        }

        float p[16];
        #pragma unroll
        for (int r = 0; r < 16; ++r) p[r] = __builtin_amdgcn_exp2f(s_cur[r]);
        float ts[8];
        #pragma unroll
        for (int r = 0; r < 8; ++r) ts[r] = p[r] + p[r+8];
        #pragma unroll
        for (int r = 0; r < 4; ++r) ts[r] += ts[r+4];
        lsum += (ts[0] + ts[1]) + (ts[2] + ts[3]);

        union { unsigned int u[4]; bf16x8 v; } pfa, pfb;
        #pragma unroll
        for (int i = 0; i < 4; ++i) pfa.u[i] = pk2(p[2*i],     p[2*i + 1]);
        #pragma unroll
        for (int i = 0; i < 4; ++i) pfb.u[i] = pk2(p[8 + 2*i], p[8 + 2*i + 1]);

        acc = __builtin_amdgcn_mfma_f32_32x32x16_bf16(v0r, pfa.v, acc, 0, 0, 0);
        acc = __builtin_amdgcn_mfma_f32_32x32x16_bf16(v1r, pfb.v, acc, 0, 0, 0);

        if (it < 15) {
            const int vn = vbeg + (it + 1) * 32;
            v0r = VLD0(vn); v1r = VLD1(vn);
            s_cur = s_next;
        }
    }
#undef KLD0
#undef KLD1
#undef VLD0
#undef VLD1
    lsum += __shfl_xor(lsum, 32);

    __shared__ float sl[4][32];
    __shared__ float sO[4][32][33];
    __shared__ float Of[32][33];

    if (hi == 0) sl[wave][wl] = lsum;
    #pragma unroll
    for (int r = 0; r < 16; ++r) {
        const int c = (r & 3) + 8*(r >> 2) + 4*hi;
        sO[wave][c][wl] = acc[r];
    }
    __syncthreads();

    {
        const int w  = threadIdx.x & 31;
        const int cg = threadIdx.x >> 5;
        const float L = (sl[0][w] + sl[1][w]) + (sl[2][w] + sl[3][w]);
        const float rL = 1.0f / L;
        #pragma unroll
        for (int cc = 0; cc < 4; ++cc) {
            const int c = cg * 4 + cc;
            const float o = ((sO[0][c][w] + sO[1][c][w]) +
                             (sO[2][c][w] + sO[3][c][w]));
            Of[c][w] = o * rL;
        }
    }
    __syncthreads();

    const float* xb = x   + (size_t)b * NC * NH * NW + w0;
    float*       ob = out + (size_t)b * NC * NH * NW + w0;
    const int chunk = threadIdx.x & 7;
    #pragma unroll
    for (int it = 0; it < 32; ++it) {
        const int row = it*32 + (threadIdx.x >> 3);
        const int c = row >> 5, h = row & 31;
        const size_t off = ((size_t)c * NH + h) * NW + chunk*4;
        const f32x4 xv = *(const f32x4*)(xb + off);
        f32x4 ov;
        ov[0] = Of[c][chunk*4 + 0] + xv[0];
        ov[1] = Of[c][chunk*4 + 1] + xv[1];
        ov[2] = Of[c][chunk*4 + 2] + xv[2];
        ov[3] = Of[c][chunk*4 + 3] + xv[3];
        __builtin_nontemporal_store(ov, (f32x4*)(ob + off));
    }
}

extern "C" void kernel_launch(void* const* d_in, const int* in_sizes, int n_in,
                              void* d_out, int out_size, void* d_ws, size_t ws_size,
                              hipStream_t stream)
{
    const float* x  = (const float*)d_in[0];
    const float* wq = (const float*)d_in[1];
    const float* bq = (const float*)d_in[2];
    const float* wk = (const float*)d_in[3];
    const float* bk = (const float*)d_in[4];
    const float* wv = (const float*)d_in[5];
    const float* bv = (const float*)d_in[6];
    float* out = (float*)d_out;

    // ws layout (bf16): qT [B][W][32] @0, kT @2MB, V [B][32][W] @4MB, wb @6MB
    char* ws = (char*)d_ws;
    __bf16* qT = (__bf16*)(ws);
    __bf16* kT = (__bf16*)(ws + (2u << 20));
    __bf16* V  = (__bf16*)(ws + (4u << 20));
    __bf16* wb = (__bf16*)(ws + (6u << 20));

    hipLaunchKernelGGL(wprep_kernel, dim3(96), dim3(256), 0, stream, wq, wk, wv, wb);
    hipLaunchKernelGGL(proj_kernel, dim3(NB * 64), dim3(384), 0, stream,
                       x, wb, bq, bk, bv, qT, kT, V);
    hipLaunchKernelGGL(attn_kernel, dim3(NB * 64), dim3(256), 0, stream,
                       x, qT, kT, V, out);
}